// Round 2
// baseline (464.924 us; speedup 1.0000x reference)
//
#include <hip/hip_runtime.h>

#define ROWS 8192
#define COLS 8192
#define TPB  512
#define EPT  16   // elements per thread (COLS / TPB)
#define VPT  4    // float4 chunks per thread
#define NW   8    // waves per block

// Monotonic float->uint key: order of keys == order of floats.
__device__ __forceinline__ unsigned f2k(float x) {
    unsigned u = __float_as_uint(x);
    return (u & 0x80000000u) ? ~u : (u | 0x80000000u);
}
__device__ __forceinline__ float k2f(unsigned k) {
    unsigned u = (k & 0x80000000u) ? (k & 0x7FFFFFFFu) : ~k;
    return __uint_as_float(u);
}

__global__ __launch_bounds__(TPB, 8)   // hard 64-VGPR cap -> 32 waves/CU
void rsoftmax_kernel(const float* __restrict__ in,
                     const float* __restrict__ rate_p,
                     float* __restrict__ out)
{
    const int t    = threadIdx.x;
    const int lane = t & 63;
    const int wave = t >> 6;
    const int row  = blockIdx.x;
    const float4* in4  = (const float4*)(in  + (size_t)row * COLS);
    float4*       out4 = (float4*)      (out + (size_t)row * COLS);

    // ---- load this thread's 16 elements into registers as ordered keys ----
    unsigned key[EPT];
    #pragma unroll
    for (int j = 0; j < VPT; ++j) {
        float4 v = in4[t + j * TPB];           // coalesced 16B/lane
        key[4*j+0] = f2k(v.x);
        key[4*j+1] = f2k(v.y);
        key[4*j+2] = f2k(v.z);
        key[4*j+3] = f2k(v.w);
    }
    // Pin keys in VGPRs: forbid the compiler from rematerializing the
    // global loads in each radix pass (round-0 VGPR_Count=36 proved it does).
    #pragma unroll
    for (int j = 0; j < EPT; ++j) asm volatile("" : "+v"(key[j]));

    // ---- rank to select: thresh = sorted_desc[idx], i.e. (idx+1)-th largest ----
    float rate = rate_p[0];
    rate = fminf(fmaxf(rate, 0.0f), 1.0f);
    int idx = (int)(rate * (float)COLS);       // trunc, like astype(int32)
    if (idx > COLS - 1) idx = COLS - 1;        // jnp.take clips
    if (idx < 0) idx = 0;

    __shared__ unsigned sHistW[NW][256];       // wave-private histograms (8 KB)
    __shared__ unsigned sWaveTot[4];           // scan waves 0..3 only
    __shared__ unsigned sK, sPfx;
    __shared__ float    sSum[NW];
    __shared__ float    sInv;

    if (t == 0) { sK = (unsigned)(idx + 1); sPfx = 0u; }

    // ---- MSB-first 4x8-bit radix select for the k-th largest key ----
    #pragma unroll
    for (int pass = 0; pass < 4; ++pass) {
        const int      s      = 24 - 8 * pass;
        const unsigned himask = (pass == 0) ? 0u : (0xFFFFFFFFu << (s + 8));

        __syncthreads();                       // sPfx/sK visible; prior reduce reads done
        const unsigned pfx = sPfx;
        const unsigned kk  = sK;

        // zero own wave's histogram — wave-local, no cross-wave sync needed
        #pragma unroll
        for (int i = 0; i < 4; ++i) sHistW[wave][lane + 64*i] = 0u;

        #pragma unroll
        for (int j = 0; j < EPT; ++j) {
            if (((key[j] ^ pfx) & himask) == 0u)
                atomicAdd(&sHistW[wave][(key[j] >> s) & 0xFFu], 1u);
        }
        __syncthreads();                       // all wave hists complete

        unsigned h = 0, v = 0;
        if (t < 256) {
            // cross-wave bin reduce: thread t owns bin t (2 lanes/bank = free)
            #pragma unroll
            for (int w = 0; w < NW; ++w) h += sHistW[w][t];

            // in-register suffix sum across the wave's 64 bins
            v = h;
            #pragma unroll
            for (int off = 1; off < 64; off <<= 1) {
                unsigned u = __shfl_down(v, off, 64);
                v += (lane + off < 64) ? u : 0u;
            }
            if (lane == 0) sWaveTot[wave] = v;
        }
        __syncthreads();

        if (t < 256) {
            unsigned above = 0u;
            #pragma unroll
            for (int w = 0; w < 4; ++w)
                if (w > wave) above += sWaveTot[w];

            const unsigned st = v + above;     // suffix[t]  = #elems with digit >= t
            const unsigned sn = st - h;        // suffix[t+1]
            if (st >= kk && sn < kk) {         // unique crossing bin
                sPfx = pfx | ((unsigned)t << s);
                sK   = kk - sn;
            }
        }
    }
    __syncthreads();
    const float thr = k2f(sPfx);

    // ---- block sum of relu(x - thr) * exp(x), all from registers ----
    float lsum = 0.0f;
    #pragma unroll
    for (int j = 0; j < EPT; ++j) {
        float x = k2f(key[j]);
        lsum += fmaxf(x - thr, 0.0f) * __expf(x);
    }
    #pragma unroll
    for (int off = 32; off > 0; off >>= 1)
        lsum += __shfl_down(lsum, off, 64);
    if (lane == 0) sSum[wave] = lsum;
    __syncthreads();
    if (t == 0) {
        float s = 0.0f;
        #pragma unroll
        for (int w = 0; w < NW; ++w) s += sSum[w];
        sInv = 1.0f / s;
    }
    __syncthreads();
    const float inv = sInv;

    // ---- normalized write, float4-coalesced (recompute exp from registers) ----
    #pragma unroll
    for (int j = 0; j < VPT; ++j) {
        float4 o;
        float x0 = k2f(key[4*j+0]); o.x = fmaxf(x0 - thr, 0.0f) * __expf(x0) * inv;
        float x1 = k2f(key[4*j+1]); o.y = fmaxf(x1 - thr, 0.0f) * __expf(x1) * inv;
        float x2 = k2f(key[4*j+2]); o.z = fmaxf(x2 - thr, 0.0f) * __expf(x2) * inv;
        float x3 = k2f(key[4*j+3]); o.w = fmaxf(x3 - thr, 0.0f) * __expf(x3) * inv;
        out4[t + j * TPB] = o;
    }
}

extern "C" void kernel_launch(void* const* d_in, const int* in_sizes, int n_in,
                              void* d_out, int out_size, void* d_ws, size_t ws_size,
                              hipStream_t stream)
{
    const float* in   = (const float*)d_in[0];
    const float* rate = (const float*)d_in[1];
    float*       out  = (float*)d_out;
    rsoftmax_kernel<<<dim3(ROWS), dim3(TPB), 0, stream>>>(in, rate, out);
}

// Round 3
// 450.161 us; speedup vs baseline: 1.0328x; 1.0328x over previous
//
#include <hip/hip_runtime.h>

#define ROWS 8192
#define COLS 8192
#define TPB  512
#define EPT  16   // elements per thread (COLS / TPB)
#define VPT  4    // float4 chunks per thread
#define NW   8    // waves per block
#define NSUB 4    // pass-0 sub-histograms per wave (lane&3)
#define HSTR 257  // sub-hist stride (pad -> copies of a bin hit 4 banks)
#define HWRD (NSUB * HSTR)   // 1028 words per wave

// Monotonic float->uint key: order of keys == order of floats.
__device__ __forceinline__ unsigned f2k(float x) {
    unsigned u = __float_as_uint(x);
    return (u & 0x80000000u) ? ~u : (u | 0x80000000u);
}
__device__ __forceinline__ float k2f(unsigned k) {
    unsigned u = (k & 0x80000000u) ? (k & 0x7FFFFFFFu) : ~k;
    return __uint_as_float(u);
}

__global__ __launch_bounds__(TPB, 8)   // 64-VGPR cap -> full wave occupancy
void rsoftmax_kernel(const float* __restrict__ in,
                     const float* __restrict__ rate_p,
                     float* __restrict__ out)
{
    const int t    = threadIdx.x;
    const int lane = t & 63;
    const int wave = t >> 6;
    const int row  = blockIdx.x;
    const float4* in4  = (const float4*)(in  + (size_t)row * COLS);
    float4*       out4 = (float4*)      (out + (size_t)row * COLS);

    // ---- load 16 elements; keep BOTH float and ordered-key forms resident ----
    unsigned key[EPT];
    float    xf[EPT];
    #pragma unroll
    for (int j = 0; j < VPT; ++j) {
        float4 v = in4[t + j * TPB];            // coalesced 16B/lane
        xf[4*j+0] = v.x;  xf[4*j+1] = v.y;
        xf[4*j+2] = v.z;  xf[4*j+3] = v.w;
        key[4*j+0] = f2k(v.x);  key[4*j+1] = f2k(v.y);
        key[4*j+2] = f2k(v.z);  key[4*j+3] = f2k(v.w);
    }
    #pragma unroll
    for (int j = 0; j < EPT; ++j) { asm volatile("" : "+v"(key[j])); asm volatile("" : "+v"(xf[j])); }

    // ---- rank: thresh = sorted_desc[idx] = (idx+1)-th largest ----
    float rate = rate_p[0];
    rate = fminf(fmaxf(rate, 0.0f), 1.0f);
    int idx = (int)(rate * (float)COLS);        // trunc, like astype(int32)
    if (idx > COLS - 1) idx = COLS - 1;         // jnp.take clips
    if (idx < 0) idx = 0;

    __shared__ unsigned sHist[NW][HWRD];        // pass0: 4 sub-hists/wave; later passes reuse sub 0
    __shared__ unsigned sWaveTot[4];
    __shared__ unsigned sK, sPfx;
    __shared__ float    sSum[NW];
    __shared__ float    sInv;

    if (t == 0) { sK = (unsigned)(idx + 1); sPfx = 0u; }
    unsigned* hw = &sHist[wave][0];

    // ================= pass 0: no predicate, no opening barrier =================
    // zero all 4 sub-hists of this wave (wave-local, no sync needed)
    #pragma unroll
    for (int i = 0; i < 17; ++i) {
        int ix = lane + 64 * i;
        if (ix < HWRD) hw[ix] = 0u;
    }
    // lane&3 picks a sub-hist; stride-257 puts the 4 copies of a bin in 4 banks.
    {
        const int sub = lane & (NSUB - 1);
        #pragma unroll
        for (int j = 0; j < EPT; ++j)
            atomicAdd(&hw[sub * HSTR + (key[j] >> 24)], 1u);
    }
    __syncthreads();                            // hists done; sK/sPfx published

    {
        const unsigned kk = sK;                 // = idx+1
        unsigned h = 0u;
        if (t < 256) {
            #pragma unroll
            for (int w = 0; w < NW; ++w)
                #pragma unroll
                for (int s2 = 0; s2 < NSUB; ++s2)
                    h += sHist[w][s2 * HSTR + t];
        }
        // in-register suffix sum over this wave's 64 bins (uniform; t>=256 adds zeros)
        unsigned v = h;
        #pragma unroll
        for (int off = 1; off < 64; off <<= 1) {
            unsigned u = __shfl_down(v, off, 64);
            v += (lane + off < 64) ? u : 0u;
        }
        if (t < 256 && lane == 0) sWaveTot[wave] = v;
        __syncthreads();
        if (t < 256) {
            unsigned above = 0u;
            #pragma unroll
            for (int w = 0; w < 4; ++w) if (w > wave) above += sWaveTot[w];
            const unsigned st = v + above;      // suffix[t]
            const unsigned sn = st - h;         // suffix[t+1]
            if (st >= kk && sn < kk) {          // unique crossing bin
                sPfx = (unsigned)t << 24;
                sK   = kk - sn;
            }
        }
    }

    // ================= passes 1..3: predicated, single hist/wave =================
    #pragma unroll
    for (int pass = 1; pass < 4; ++pass) {
        const int      s      = 24 - 8 * pass;
        const unsigned himask = 0xFFFFFFFFu << (s + 8);

        __syncthreads();                        // publish sPfx/sK; prior reduce reads done
        const unsigned pfx = sPfx;
        const unsigned kk  = sK;

        hw[lane] = 0u; hw[lane + 64] = 0u; hw[lane + 128] = 0u; hw[lane + 192] = 0u;
        #pragma unroll
        for (int j = 0; j < EPT; ++j) {
            if (((key[j] ^ pfx) & himask) == 0u)
                atomicAdd(&hw[(key[j] >> s) & 0xFFu], 1u);
        }
        __syncthreads();

        unsigned h = 0u;
        if (t < 256) {
            #pragma unroll
            for (int w = 0; w < NW; ++w) h += sHist[w][t];
        }
        unsigned v = h;
        #pragma unroll
        for (int off = 1; off < 64; off <<= 1) {
            unsigned u = __shfl_down(v, off, 64);
            v += (lane + off < 64) ? u : 0u;
        }
        if (t < 256 && lane == 0) sWaveTot[wave] = v;
        __syncthreads();
        if (t < 256) {
            unsigned above = 0u;
            #pragma unroll
            for (int w = 0; w < 4; ++w) if (w > wave) above += sWaveTot[w];
            const unsigned st = v + above;
            const unsigned sn = st - h;
            if (st >= kk && sn < kk) {
                sPfx = pfx | ((unsigned)t << s);
                sK   = kk - sn;
            }
        }
    }
    __syncthreads();
    const float thr = k2f(sPfx);

    // ---- block sum of relu(x - thr) * exp(x): floats straight from registers ----
    float lsum = 0.0f;
    #pragma unroll
    for (int j = 0; j < EPT; ++j)
        lsum += fmaxf(xf[j] - thr, 0.0f) * __expf(xf[j]);
    #pragma unroll
    for (int off = 32; off > 0; off >>= 1)
        lsum += __shfl_down(lsum, off, 64);
    if (lane == 0) sSum[wave] = lsum;
    __syncthreads();
    if (t == 0) {
        float s = 0.0f;
        #pragma unroll
        for (int w = 0; w < NW; ++w) s += sSum[w];
        sInv = 1.0f / s;
    }
    __syncthreads();
    const float inv = sInv;

    // ---- normalized write, float4-coalesced ----
    #pragma unroll
    for (int j = 0; j < VPT; ++j) {
        float4 o;
        o.x = fmaxf(xf[4*j+0] - thr, 0.0f) * __expf(xf[4*j+0]) * inv;
        o.y = fmaxf(xf[4*j+1] - thr, 0.0f) * __expf(xf[4*j+1]) * inv;
        o.z = fmaxf(xf[4*j+2] - thr, 0.0f) * __expf(xf[4*j+2]) * inv;
        o.w = fmaxf(xf[4*j+3] - thr, 0.0f) * __expf(xf[4*j+3]) * inv;
        out4[t + j * TPB] = o;
    }
}

extern "C" void kernel_launch(void* const* d_in, const int* in_sizes, int n_in,
                              void* d_out, int out_size, void* d_ws, size_t ws_size,
                              hipStream_t stream)
{
    const float* in   = (const float*)d_in[0];
    const float* rate = (const float*)d_in[1];
    float*       out  = (float*)d_out;
    rsoftmax_kernel<<<dim3(ROWS), dim3(TPB), 0, stream>>>(in, rate, out);
}